// Round 4
// baseline (1155.712 us; speedup 1.0000x reference)
//
#include <hip/hip_runtime.h>

#define NN 12288
#define INF_ 128
#define OUTF 64
#define ALPHA 0.2f
#define C1 6.0f
#define KCH (NN / 4)  /* 3072 per wave */

typedef unsigned short u16;
typedef unsigned int u32;
typedef _Float16 half8 __attribute__((ext_vector_type(8)));
typedef float floatx4 __attribute__((ext_vector_type(4)));
typedef int intx4 __attribute__((ext_vector_type(4)));

union H16 { u16 u; _Float16 h; };
__device__ __forceinline__ u16 f2h(float f) { H16 c; c.h = (_Float16)f; return c.u; }
__device__ __forceinline__ float h2f(u16 u) { H16 c; c.u = u; return (float)c.h; }

// ---------------- K1: h = X@W (fp32), scalars, Bt (128 x NN fp16) ------------------------
// Bt rows 0-63 : exp(s2_j - C1) * h_j[c]   (pos-branch numerator, fp16)
//         64-127: exp(ALPHA*s2_j) * h_j[c] (neg-branch numerator, fp16)
// thg[j] = exp(-s1_j - C1)   (branch threshold:  pos  iff  e1_j > thg[i])
// f1g[j] = exp(s1_j + C1), f2g[j] = exp(ALPHA*s1_j)
// e12g[j] = packed half2 {exp(s2_j - C1), exp(ALPHA*s2_j)} for VALU denominator accum
__global__ __launch_bounds__(256) void k1_prep(
    const float* __restrict__ inp, const float* __restrict__ W, const float* __restrict__ a,
    float* __restrict__ thg, float* __restrict__ f1g, float* __restrict__ f2g,
    u32* __restrict__ e12g, u16* __restrict__ Bt)
{
  const int tid = threadIdx.x, wave = tid >> 6, lane = tid & 63;
  float wcol[INF_];
#pragma unroll
  for (int k = 0; k < INF_; ++k) wcol[k] = W[k * OUTF + lane];
  const float a1l = a[lane];
  const float a2l = a[OUTF + lane];
  const int row0 = blockIdx.x * 64 + wave * 16;
  for (int r = 0; r < 16; ++r) {
    const int j = row0 + r;
    const float4* ip4 = reinterpret_cast<const float4*>(inp + (size_t)j * INF_);
    float h = 0.f;
#pragma unroll
    for (int c = 0; c < INF_ / 4; ++c) {
      float4 v = ip4[c];
      const int k = c * 4;
      h += v.x * wcol[k] + v.y * wcol[k + 1] + v.z * wcol[k + 2] + v.w * wcol[k + 3];
    }
    float p1 = h * a1l, p2 = h * a2l;
#pragma unroll
    for (int off = 32; off > 0; off >>= 1) {
      p1 += __shfl_xor(p1, off);
      p2 += __shfl_xor(p2, off);
    }
    const float s1 = p1, s2 = p2;          // all 64 lanes hold the full sums
    const float e1 = expf(s2 - C1);
    const float e2 = expf(ALPHA * s2);
    Bt[(size_t)lane * NN + j]        = f2h(e1 * h);
    Bt[(size_t)(64 + lane) * NN + j] = f2h(e2 * h);
    if (lane == 0) {
      thg[j]  = expf(-s1 - C1);
      f1g[j]  = expf(s1 + C1);
      f2g[j]  = expf(ALPHA * s1);
      e12g[j] = (u32)f2h(e1) | ((u32)f2h(e2) << 16);
    }
  }
}

// ---------------- K2: masked dual GEMM + VALU denominators + in-LDS reduce ---------------
// grid = 768 blocks; block b owns output rows [b*16, b*16+16); wave w owns K-chunk w.
__global__ __launch_bounds__(256, 3) void k2_main(
    const int* __restrict__ adj, const u16* __restrict__ Bt,
    const float* __restrict__ thg, const float* __restrict__ f1g,
    const float* __restrict__ f2g, const u32* __restrict__ e12g,
    float* __restrict__ out)
{
  __shared__ float red[4][16][132];        // 33.8 KB numerators
  __shared__ float dred[4][16][2];         // denominators (wave, row, {d1,d2})
  const int tid = threadIdx.x;
  const int wave = tid >> 6, lane = tid & 63;
  const int quad = lane >> 4, lr = lane & 15;
  const int mbase = (int)blockIdx.x * 16;
  const int ia = mbase + lr;               // A-operand row for this lane
  const float th = thg[ia];
  const int k0 = wave * KCH;
  const int* arow = adj + (size_t)ia * NN;

  floatx4 acc[8];
#pragma unroll
  for (int n = 0; n < 8; ++n) acc[n] = (floatx4){0.f, 0.f, 0.f, 0.f};
  float d1 = 0.f, d2 = 0.f;

  for (int kb = k0; kb < k0 + KCH; kb += 64) {
#pragma unroll
    for (int half = 0; half < 2; ++half) {
      const int kq = kb + half * 32 + quad * 8;
      intx4 av0 = __builtin_nontemporal_load(reinterpret_cast<const intx4*>(arow + kq));
      intx4 av1 = __builtin_nontemporal_load(reinterpret_cast<const intx4*>(arow + kq) + 1);
      uint4 ev0 = *reinterpret_cast<const uint4*>(e12g + kq);
      uint4 ev1 = *reinterpret_cast<const uint4*>(e12g + kq + 4);
      const int aj[8] = {av0.x, av0.y, av0.z, av0.w, av1.x, av1.y, av1.z, av1.w};
      const u32 ee[8] = {ev0.x, ev0.y, ev0.z, ev0.w, ev1.x, ev1.y, ev1.z, ev1.w};
      union { half8 v; u16 s[8]; } A1, A2;
#pragma unroll
      for (int e = 0; e < 8; ++e) {
        const float e1f = h2f((u16)(ee[e] & 0xFFFFu));
        const float e2f = h2f((u16)(ee[e] >> 16));
        const bool nb = aj[e] > 0;
        const bool up = e1f > th;           // == (s2_j > -s1_i), monotone transform
        const bool m1 = nb && up, m2 = nb && !up;
        A1.s[e] = m1 ? (u16)0x3C00 : (u16)0;   // fp16 1.0 / 0.0
        A2.s[e] = m2 ? (u16)0x3C00 : (u16)0;
        d1 += m1 ? e1f : 0.f;
        d2 += m2 ? e2f : 0.f;
      }
      const u16* bp = Bt + kq;
#pragma unroll
      for (int n = 0; n < 8; ++n) {
        half8 Bv = *reinterpret_cast<const half8*>(bp + (size_t)(n * 16 + lr) * NN);
        acc[n] = __builtin_amdgcn_mfma_f32_16x16x32_f16(n < 4 ? A1.v : A2.v, Bv, acc[n], 0, 0, 0);
      }
    }
  }

  // numerators: C/D layout col = lane&15, row = quad*4 + reg
#pragma unroll
  for (int n = 0; n < 8; ++n)
#pragma unroll
    for (int r = 0; r < 4; ++r)
      red[wave][quad * 4 + r][n * 16 + lr] = acc[n][r];
  // denominators: combine the 4 quads of this wave (lanes lr, lr+16, lr+32, lr+48)
  d1 += __shfl_xor(d1, 16); d1 += __shfl_xor(d1, 32);
  d2 += __shfl_xor(d2, 16); d2 += __shfl_xor(d2, 32);
  if (lane < 16) { dred[wave][lane][0] = d1; dred[wave][lane][1] = d2; }
  __syncthreads();

  // reduce 4 K-chunks, combine branches, divide, ELU, store fp32
#pragma unroll
  for (int it = 0; it < 4; ++it) {
    const int idx = tid + it * 256;
    const int row = idx >> 6, col = idx & 63;
    float n1 = 0.f, n2 = 0.f, dd1 = 0.f, dd2 = 0.f;
#pragma unroll
    for (int w = 0; w < 4; ++w) {
      n1 += red[w][row][col];
      n2 += red[w][row][64 + col];
      dd1 += dred[w][row][0];
      dd2 += dred[w][row][1];
    }
    const float f1 = f1g[mbase + row], f2 = f2g[mbase + row];
    const float num = f1 * n1 + f2 * n2;
    const float den = fmaxf(f1 * dd1 + f2 * dd2, 1e-30f);
    const float x = num / den;
    const float y = x > 0.f ? x : (expf(x) - 1.f);
    out[(size_t)(mbase + row) * OUTF + col] = y;
  }
}

extern "C" void kernel_launch(void* const* d_in, const int* in_sizes, int n_in,
                              void* d_out, int out_size, void* d_ws, size_t ws_size,
                              hipStream_t stream) {
  const float* inp = (const float*)d_in[0];
  const int* adj = (const int*)d_in[1];
  const float* W = (const float*)d_in[2];
  const float* a = (const float*)d_in[3];

  // Workspace: Bt 128x12288 fp16 (3,145,728 B) + 4 fp32/u32 scalar arrays (49,152 B each)
  u16* Bt = (u16*)d_ws;
  char* base = (char*)d_ws + (size_t)128 * NN * 2;
  float* thg = (float*)(base);
  float* f1g = (float*)(base + 49152);
  float* f2g = (float*)(base + 2 * 49152);
  u32* e12g = (u32*)(base + 3 * 49152);

  k1_prep<<<192, 256, 0, stream>>>(inp, W, a, thg, f1g, f2g, e12g, Bt);
  k2_main<<<768, 256, 0, stream>>>(adj, Bt, thg, f1g, f2g, e12g, (float*)d_out);
}